// Round 3
// baseline (841.305 us; speedup 1.0000x reference)
//
#include <hip/hip_runtime.h>
#include <math.h>

#define DIM 1024
#define HID 4096
#define NE 8
#define NTOK 4096

typedef short s16x8 __attribute__((ext_vector_type(8)));
typedef float f32x4 __attribute__((ext_vector_type(4)));

// fp32 -> bf16 round-to-nearest-even, bit-level
__device__ __forceinline__ unsigned short f2bf(float f) {
  unsigned int u = __float_as_uint(f);
  u = u + 0x7fffu + ((u >> 16) & 1u);
  return (unsigned short)(u >> 16);
}

__device__ __forceinline__ void gll16(const void* g, void* l) {
  __builtin_amdgcn_global_load_lds(
      (const __attribute__((address_space(1))) unsigned int*)g,
      (__attribute__((address_space(3))) unsigned int*)l, 16, 0, 0);
}

// ---------------- zero: d_out + control ints ----------------
__global__ __launch_bounds__(256) void zero_k(float4* out4, int* ctrl) {
  int i = blockIdx.x * 256 + threadIdx.x;
  out4[i] = make_float4(0.f, 0.f, 0.f, 0.f);
  if (i < 32) ctrl[i] = 0;
}

// ---------------- router: logits, top-2, softmax, x->bf16 ----------------
// ctrl[0..8): counts  ctrl[8..17): offsets  ctrl[20..28): cursors
__global__ __launch_bounds__(256) void router_k(const float* __restrict__ x,
    const float* __restrict__ Wr, const float* __restrict__ br,
    short* __restrict__ xbf, int* __restrict__ ctrl,
    int* __restrict__ sel, float* __restrict__ selw) {
  __shared__ float lred[4 * NE];
  int t = blockIdx.x, tid = threadIdx.x;
  const float* xr = x + (size_t)t * DIM;
  float p[NE];
#pragma unroll
  for (int e = 0; e < NE; ++e) p[e] = 0.f;
#pragma unroll
  for (int it = 0; it < DIM / 256; ++it) {
    int d = it * 256 + tid;
    float xv = xr[d];
    xbf[(size_t)t * DIM + d] = (short)f2bf(xv);
#pragma unroll
    for (int e = 0; e < NE; ++e) p[e] += xv * Wr[d * NE + e];
  }
#pragma unroll
  for (int e = 0; e < NE; ++e) {
    float v = p[e];
#pragma unroll
    for (int off = 32; off > 0; off >>= 1) v += __shfl_down(v, off);
    if ((tid & 63) == 0) lred[(tid >> 6) * NE + e] = v;
  }
  __syncthreads();
  if (tid == 0) {
    float lg[NE];
#pragma unroll
    for (int e = 0; e < NE; ++e)
      lg[e] = lred[e] + lred[NE + e] + lred[2 * NE + e] + lred[3 * NE + e] + br[e];
    int b0 = 0; float v0 = lg[0];
    for (int e = 1; e < NE; ++e) if (lg[e] > v0) { v0 = lg[e]; b0 = e; }
    int b1i = -1; float v1 = -3.4e38f;
    for (int e = 0; e < NE; ++e) if (e != b0 && lg[e] > v1) { v1 = lg[e]; b1i = e; }
    float e1 = expf(v1 - v0);
    float inv = 1.f / (1.f + e1);
    sel[t * 2] = b0; sel[t * 2 + 1] = b1i;
    selw[t * 2] = inv; selw[t * 2 + 1] = e1 * inv;
    atomicAdd(&ctrl[b0], 1); atomicAdd(&ctrl[b1i], 1);
  }
}

// ---------------- scan: offsets ----------------
__global__ void scan_k(int* ctrl) {
  if (threadIdx.x == 0) {
    int o = 0;
#pragma unroll
    for (int e = 0; e < NE; ++e) { ctrl[8 + e] = o; o += ctrl[e]; }
    ctrl[16] = o;
  }
}

// ---------------- build: compact per-expert token lists ----------------
__global__ __launch_bounds__(256) void build_k(const int* __restrict__ sel,
    const float* __restrict__ selw, int* ctrl,
    int* __restrict__ slot_tok, float* __restrict__ slot_w) {
  int t = blockIdx.x * 256 + threadIdx.x;
  if (t >= NTOK) return;
#pragma unroll
  for (int k = 0; k < 2; ++k) {
    int e = sel[t * 2 + k];
    int pos = atomicAdd(&ctrl[20 + e], 1);
    int s = ctrl[8 + e] + pos;
    slot_tok[s] = t;
    slot_w[s] = selw[t * 2 + k];
  }
}

// ---------------- tcvt: fp32 [e][K][N] -> bf16 [e][N][K] (transpose+convert) ----
__global__ __launch_bounds__(256) void tcvt_k(const float* __restrict__ src,
    short* __restrict__ dst, int K, int N) {
  __shared__ __attribute__((aligned(16))) short t[64][72];
  int e = blockIdx.z;
  int n0 = blockIdx.x * 64, k0 = blockIdx.y * 64;
  const float* s = src + (size_t)e * K * N;
  short* d = dst + (size_t)e * N * K;
  int tid = threadIdx.x;
#pragma unroll
  for (int i = 0; i < 4; ++i) {
    int c = tid + i * 256;           // 0..1023
    int row = c >> 4, c4 = c & 15;   // k-row, float4 col chunk
    float4 v = *(const float4*)&s[(size_t)(k0 + row) * N + n0 + c4 * 4];
    t[c4 * 4 + 0][row] = (short)f2bf(v.x);
    t[c4 * 4 + 1][row] = (short)f2bf(v.y);
    t[c4 * 4 + 2][row] = (short)f2bf(v.z);
    t[c4 * 4 + 3][row] = (short)f2bf(v.w);
  }
  __syncthreads();
#pragma unroll
  for (int i = 0; i < 2; ++i) {
    int c = tid + i * 256;           // 0..511
    int n = c >> 3, k8 = c & 7;
    *(s16x8*)&d[(size_t)(n0 + n) * K + k0 + k8 * 8] = *(const s16x8*)&t[n][k8 * 8];
  }
}

// ---------------- GEMM1 (new): h = gelu(gather(x) @ W1 + b1) ----------------
// m97-shape: dbuf LDS, gll16 both operands, 1 barrier/K-step, XOR chunk swizzle.
// grid (HID/128, NTOK/128, NE), block 256.
__global__ __launch_bounds__(256) void gemm1n_k(const short* __restrict__ xbf,
    const short* __restrict__ w1t, const float* __restrict__ b1,
    const int* __restrict__ ctrl, const int* __restrict__ slot_tok,
    short* __restrict__ h) {
  int e = blockIdx.z, my = blockIdx.y, bx = blockIdx.x;
  int cnt = ctrl[e];
  if (my * 128 >= cnt) return;
  int slot0 = ctrl[8 + e];
  int tid = threadIdx.x, lane = tid & 63;
  int wv = tid >> 6, wm = wv >> 1, wn = wv & 1;
  __shared__ __attribute__((aligned(16))) short ldsA[2][128 * 32];
  __shared__ __attribute__((aligned(16))) short ldsB[2][128 * 32];

  const short* ga[2]; const short* gb[2]; int lo[2];
#pragma unroll
  for (int i = 0; i < 2; ++i) {
    int c = tid + i * 256;
    int row = c >> 2;
    int cs = (c & 3) ^ (row & 3);    // source chunk pre-swizzle (involution)
    int srow = min(my * 128 + row, cnt - 1);
    ga[i] = xbf + (size_t)slot_tok[slot0 + srow] * DIM + cs * 8;
    gb[i] = w1t + ((size_t)e * HID + bx * 128 + row) * DIM + cs * 8;
    lo[i] = c * 8;
  }
  int koff = ((lane >> 4) ^ (lane & 3)) * 8;  // swizzled read chunk

  f32x4 acc[4][4];
#pragma unroll
  for (int i = 0; i < 4; ++i)
#pragma unroll
    for (int j = 0; j < 4; ++j) acc[i][j] = (f32x4){0.f, 0.f, 0.f, 0.f};

#pragma unroll
  for (int i = 0; i < 2; ++i) { gll16(ga[i], &ldsA[0][lo[i]]); gll16(gb[i], &ldsB[0][lo[i]]); }
  __syncthreads();

  const int NT = DIM / 32;
  for (int t = 0; t < NT; ++t) {
    int buf = t & 1;
    if (t + 1 < NT) {
      int nb = buf ^ 1;
#pragma unroll
      for (int i = 0; i < 2; ++i) {
        gll16(ga[i] + (t + 1) * 32, &ldsA[nb][lo[i]]);
        gll16(gb[i] + (t + 1) * 32, &ldsB[nb][lo[i]]);
      }
    }
    s16x8 aF[4], bF[4];
#pragma unroll
    for (int i = 0; i < 4; ++i)
      aF[i] = *(const s16x8*)&ldsA[buf][(wm * 64 + i * 16 + (lane & 15)) * 32 + koff];
#pragma unroll
    for (int j = 0; j < 4; ++j)
      bF[j] = *(const s16x8*)&ldsB[buf][(wn * 64 + j * 16 + (lane & 15)) * 32 + koff];
#pragma unroll
    for (int i = 0; i < 4; ++i)
#pragma unroll
      for (int j = 0; j < 4; ++j)
        acc[i][j] = __builtin_amdgcn_mfma_f32_16x16x32_bf16(aF[i], bF[j], acc[i][j], 0, 0, 0);
    __syncthreads();  // drains stage(t+1) vmcnt + all ds_reads of buf
  }
#pragma unroll
  for (int i = 0; i < 4; ++i) {
#pragma unroll
    for (int r = 0; r < 4; ++r) {
      int row_l = wm * 64 + i * 16 + (lane >> 4) * 4 + r;
      int grow = my * 128 + row_l;
      if (grow < cnt) {
#pragma unroll
        for (int j = 0; j < 4; ++j) {
          int col = bx * 128 + wn * 64 + j * 16 + (lane & 15);
          float z = acc[i][j][r] + b1[e * HID + col];
          float g = 0.5f * z * (1.f + erff(z * 0.70710678118f));
          h[(size_t)(slot0 + grow) * HID + col] = (short)f2bf(g);
        }
      }
    }
  }
}

// ---------------- GEMM2 (new): out += w * (h @ W2 + b2), K-split x4 ------------
// grid (8*4, NTOK/128, NE): bx&7 = n-tile, bx>>3 = K-chunk.
__global__ __launch_bounds__(256) void gemm2n_k(const short* __restrict__ h,
    const short* __restrict__ w2t, const float* __restrict__ b2,
    const int* __restrict__ ctrl, const int* __restrict__ slot_tok,
    const float* __restrict__ slot_w, float* __restrict__ out) {
  int e = blockIdx.z, my = blockIdx.y;
  int nx = blockIdx.x & 7, kc = blockIdx.x >> 3;
  int cnt = ctrl[e];
  if (my * 128 >= cnt) return;
  int slot0 = ctrl[8 + e];
  int tid = threadIdx.x, lane = tid & 63;
  int wv = tid >> 6, wm = wv >> 1, wn = wv & 1;
  __shared__ __attribute__((aligned(16))) short ldsA[2][128 * 32];
  __shared__ __attribute__((aligned(16))) short ldsB[2][128 * 32];
  __shared__ int stok[128];
  __shared__ float swt[128];
  if (tid < 128) {
    int srow = min(my * 128 + tid, cnt - 1);
    stok[tid] = slot_tok[slot0 + srow];
    swt[tid] = slot_w[slot0 + srow];
  }
  int k0 = kc * (HID / 4);
  const short* ga[2]; const short* gb[2]; int lo[2];
#pragma unroll
  for (int i = 0; i < 2; ++i) {
    int c = tid + i * 256;
    int row = c >> 2;
    int cs = (c & 3) ^ (row & 3);
    int srow = min(my * 128 + row, cnt - 1);
    ga[i] = h + (size_t)(slot0 + srow) * HID + k0 + cs * 8;
    gb[i] = w2t + ((size_t)e * DIM + nx * 128 + row) * HID + k0 + cs * 8;
    lo[i] = c * 8;
  }
  int koff = ((lane >> 4) ^ (lane & 3)) * 8;

  f32x4 acc[4][4];
#pragma unroll
  for (int i = 0; i < 4; ++i)
#pragma unroll
    for (int j = 0; j < 4; ++j) acc[i][j] = (f32x4){0.f, 0.f, 0.f, 0.f};

#pragma unroll
  for (int i = 0; i < 2; ++i) { gll16(ga[i], &ldsA[0][lo[i]]); gll16(gb[i], &ldsB[0][lo[i]]); }
  __syncthreads();

  const int NT = (HID / 4) / 32;
  for (int t = 0; t < NT; ++t) {
    int buf = t & 1;
    if (t + 1 < NT) {
      int nb = buf ^ 1;
#pragma unroll
      for (int i = 0; i < 2; ++i) {
        gll16(ga[i] + (t + 1) * 32, &ldsA[nb][lo[i]]);
        gll16(gb[i] + (t + 1) * 32, &ldsB[nb][lo[i]]);
      }
    }
    s16x8 aF[4], bF[4];
#pragma unroll
    for (int i = 0; i < 4; ++i)
      aF[i] = *(const s16x8*)&ldsA[buf][(wm * 64 + i * 16 + (lane & 15)) * 32 + koff];
#pragma unroll
    for (int j = 0; j < 4; ++j)
      bF[j] = *(const s16x8*)&ldsB[buf][(wn * 64 + j * 16 + (lane & 15)) * 32 + koff];
#pragma unroll
    for (int i = 0; i < 4; ++i)
#pragma unroll
      for (int j = 0; j < 4; ++j)
        acc[i][j] = __builtin_amdgcn_mfma_f32_16x16x32_bf16(aF[i], bF[j], acc[i][j], 0, 0, 0);
    __syncthreads();
  }
#pragma unroll
  for (int i = 0; i < 4; ++i) {
#pragma unroll
    for (int r = 0; r < 4; ++r) {
      int row_l = wm * 64 + i * 16 + (lane >> 4) * 4 + r;
      int grow = my * 128 + row_l;
      if (grow < cnt) {
        int tok = stok[row_l];
        float wrow = swt[row_l];
#pragma unroll
        for (int j = 0; j < 4; ++j) {
          int col = nx * 128 + wn * 64 + j * 16 + (lane & 15);
          float y = acc[i][j][r];
          if (kc == 0) y += b2[e * DIM + col];
          unsafeAtomicAdd(&out[(size_t)tok * DIM + col], wrow * y);
        }
      }
    }
  }
}

// ================= fallback (round-2, passed) GEMMs: used if ws too small ======
__global__ __launch_bounds__(256) void gemm1_k(const short* __restrict__ xbf,
    const float* __restrict__ W1, const float* __restrict__ b1,
    const int* __restrict__ ctrl, const int* __restrict__ slot_tok,
    short* __restrict__ h) {
  int e = blockIdx.z, my = blockIdx.y, bx = blockIdx.x;
  int cnt = ctrl[e];
  if (my * 128 >= cnt) return;
  int slot0 = ctrl[8 + e];
  int tid = threadIdx.x, lane = tid & 63;
  int wv = tid >> 6, wm = wv >> 1, wn = wv & 1;
  __shared__ __attribute__((aligned(16))) short ldsA[128 * 32];
  __shared__ __attribute__((aligned(16))) short ldsB[128 * 40];
  const short* ap[2]; short* la[2];
#pragma unroll
  for (int i = 0; i < 2; ++i) {
    int c = tid + i * 256;
    int row = c >> 2;
    int srow = min(my * 128 + row, cnt - 1);
    int tok = slot_tok[slot0 + srow];
    ap[i] = xbf + (size_t)tok * DIM + (c & 3) * 8;
    la[i] = &ldsA[c * 8];
  }
  int n0 = (tid & 63) * 2;
  int kg = tid >> 6;
  const float* bp = W1 + ((size_t)e * DIM + kg * 8) * HID + bx * 128 + n0;
  short* lb0 = &ldsB[(n0) * 40 + kg * 8];
  short* lb1 = &ldsB[(n0 + 1) * 40 + kg * 8];
  f32x4 acc[4][4];
#pragma unroll
  for (int i = 0; i < 4; ++i)
#pragma unroll
    for (int j = 0; j < 4; ++j) acc[i][j] = (f32x4){0.f, 0.f, 0.f, 0.f};
#pragma unroll 2
  for (int kt = 0; kt < DIM / 32; ++kt) {
    float2 fv[8];
#pragma unroll
    for (int kk = 0; kk < 8; ++kk) fv[kk] = *(const float2*)&bp[(size_t)kk * HID];
    __syncthreads();
    gll16(ap[0], la[0]); gll16(ap[1], la[1]);
    s16x8 v0, v1;
#pragma unroll
    for (int kk = 0; kk < 8; ++kk) { v0[kk] = (short)f2bf(fv[kk].x); v1[kk] = (short)f2bf(fv[kk].y); }
    *(s16x8*)lb0 = v0; *(s16x8*)lb1 = v1;
    asm volatile("s_waitcnt vmcnt(0)" ::: "memory");
    __syncthreads();
    s16x8 aF[4], bF[4];
#pragma unroll
    for (int i = 0; i < 4; ++i)
      aF[i] = *(const s16x8*)&ldsA[(wm * 64 + i * 16 + (lane & 15)) * 32 + (lane >> 4) * 8];
#pragma unroll
    for (int j = 0; j < 4; ++j)
      bF[j] = *(const s16x8*)&ldsB[(wn * 64 + j * 16 + (lane & 15)) * 40 + (lane >> 4) * 8];
#pragma unroll
    for (int i = 0; i < 4; ++i)
#pragma unroll
      for (int j = 0; j < 4; ++j)
        acc[i][j] = __builtin_amdgcn_mfma_f32_16x16x32_bf16(aF[i], bF[j], acc[i][j], 0, 0, 0);
    ap[0] += 32; ap[1] += 32; bp += (size_t)32 * HID;
  }
#pragma unroll
  for (int i = 0; i < 4; ++i)
#pragma unroll
    for (int r = 0; r < 4; ++r) {
      int row_l = wm * 64 + i * 16 + (lane >> 4) * 4 + r;
      int grow = my * 128 + row_l;
      if (grow < cnt)
#pragma unroll
        for (int j = 0; j < 4; ++j) {
          int col = bx * 128 + wn * 64 + j * 16 + (lane & 15);
          float z = acc[i][j][r] + b1[e * HID + col];
          float g = 0.5f * z * (1.f + erff(z * 0.70710678118f));
          h[(size_t)(slot0 + grow) * HID + col] = (short)f2bf(g);
        }
    }
}

__global__ __launch_bounds__(256) void gemm2_k(const short* __restrict__ h,
    const float* __restrict__ W2, const float* __restrict__ b2,
    const int* __restrict__ ctrl, const int* __restrict__ slot_tok,
    const float* __restrict__ slot_w, float* __restrict__ out) {
  int e = blockIdx.z, my = blockIdx.y, bx = blockIdx.x;
  int cnt = ctrl[e];
  if (my * 128 >= cnt) return;
  int slot0 = ctrl[8 + e];
  int tid = threadIdx.x, lane = tid & 63;
  int wv = tid >> 6, wm = wv >> 1, wn = wv & 1;
  __shared__ __attribute__((aligned(16))) short ldsA[128 * 32];
  __shared__ __attribute__((aligned(16))) short ldsB[128 * 40];
  __shared__ int stok[128];
  __shared__ float swt[128];
  if (tid < 128) {
    int srow = min(my * 128 + tid, cnt - 1);
    stok[tid] = slot_tok[slot0 + srow];
    swt[tid] = slot_w[slot0 + srow];
  }
  const short* ap[2]; short* la[2];
#pragma unroll
  for (int i = 0; i < 2; ++i) {
    int c = tid + i * 256;
    int row = c >> 2;
    int srow = min(my * 128 + row, cnt - 1);
    ap[i] = h + (size_t)(slot0 + srow) * HID + (c & 3) * 8;
    la[i] = &ldsA[c * 8];
  }
  int n0 = (tid & 63) * 2;
  int kg = tid >> 6;
  const float* bp = W2 + ((size_t)e * HID + kg * 8) * DIM + bx * 128 + n0;
  short* lb0 = &ldsB[(n0) * 40 + kg * 8];
  short* lb1 = &ldsB[(n0 + 1) * 40 + kg * 8];
  f32x4 acc[4][4];
#pragma unroll
  for (int i = 0; i < 4; ++i)
#pragma unroll
    for (int j = 0; j < 4; ++j) acc[i][j] = (f32x4){0.f, 0.f, 0.f, 0.f};
#pragma unroll 2
  for (int kt = 0; kt < HID / 32; ++kt) {
    float2 fv[8];
#pragma unroll
    for (int kk = 0; kk < 8; ++kk) fv[kk] = *(const float2*)&bp[(size_t)kk * DIM];
    __syncthreads();
    gll16(ap[0], la[0]); gll16(ap[1], la[1]);
    s16x8 v0, v1;
#pragma unroll
    for (int kk = 0; kk < 8; ++kk) { v0[kk] = (short)f2bf(fv[kk].x); v1[kk] = (short)f2bf(fv[kk].y); }
    *(s16x8*)lb0 = v0; *(s16x8*)lb1 = v1;
    asm volatile("s_waitcnt vmcnt(0)" ::: "memory");
    __syncthreads();
    s16x8 aF[4], bF[4];
#pragma unroll
    for (int i = 0; i < 4; ++i)
      aF[i] = *(const s16x8*)&ldsA[(wm * 64 + i * 16 + (lane & 15)) * 32 + (lane >> 4) * 8];
#pragma unroll
    for (int j = 0; j < 4; ++j)
      bF[j] = *(const s16x8*)&ldsB[(wn * 64 + j * 16 + (lane & 15)) * 40 + (lane >> 4) * 8];
#pragma unroll
    for (int i = 0; i < 4; ++i)
#pragma unroll
      for (int j = 0; j < 4; ++j)
        acc[i][j] = __builtin_amdgcn_mfma_f32_16x16x32_bf16(aF[i], bF[j], acc[i][j], 0, 0, 0);
    ap[0] += 32; ap[1] += 32; bp += (size_t)32 * DIM;
  }
#pragma unroll
  for (int i = 0; i < 4; ++i)
#pragma unroll
    for (int r = 0; r < 4; ++r) {
      int row_l = wm * 64 + i * 16 + (lane >> 4) * 4 + r;
      int grow = my * 128 + row_l;
      if (grow < cnt) {
        int tok = stok[row_l];
        float wrow = swt[row_l];
#pragma unroll
        for (int j = 0; j < 4; ++j) {
          int col = bx * 128 + wn * 64 + j * 16 + (lane & 15);
          float y = acc[i][j][r] + b2[e * DIM + col];
          unsafeAtomicAdd(&out[(size_t)tok * DIM + col], wrow * y);
        }
      }
    }
}

extern "C" void kernel_launch(void* const* d_in, const int* in_sizes, int n_in,
                              void* d_out, int out_size, void* d_ws, size_t ws_size,
                              hipStream_t stream) {
  const float* x  = (const float*)d_in[0];
  const float* Wr = (const float*)d_in[1];
  const float* br = (const float*)d_in[2];
  const float* W1 = (const float*)d_in[3];
  const float* b1 = (const float*)d_in[4];
  const float* W2 = (const float*)d_in[5];
  const float* b2 = (const float*)d_in[6];
  float* out = (float*)d_out;

  char* ws = (char*)d_ws;
  const size_t MiB = 1024 * 1024;
  int*   ctrl     = (int*)(ws);
  int*   sel      = (int*)(ws + 1024);
  float* selw     = (float*)(ws + 33792);
  int*   slot_tok = (int*)(ws + 66560);
  float* slot_w   = (float*)(ws + 99328);
  short* xbf      = (short*)(ws + 1 * MiB);    // 8 MiB
  short* h        = (short*)(ws + 16 * MiB);   // 64 MiB
  short* w1t      = (short*)(ws + 80 * MiB);   // 64 MiB  [e][HID][DIM] bf16
  short* w2t      = (short*)(ws + 144 * MiB);  // 64 MiB  [e][DIM][HID] bf16
  bool fat = ws_size >= 208 * MiB;

  zero_k<<<(NTOK * DIM / 4) / 256, 256, 0, stream>>>((float4*)out, ctrl);
  router_k<<<NTOK, 256, 0, stream>>>(x, Wr, br, xbf, ctrl, sel, selw);
  scan_k<<<1, 64, 0, stream>>>(ctrl);
  build_k<<<NTOK / 256, 256, 0, stream>>>(sel, selw, ctrl, slot_tok, slot_w);
  if (fat) {
    tcvt_k<<<dim3(HID / 64, DIM / 64, NE), 256, 0, stream>>>(W1, w1t, DIM, HID);
    tcvt_k<<<dim3(DIM / 64, HID / 64, NE), 256, 0, stream>>>(W2, w2t, HID, DIM);
    gemm1n_k<<<dim3(HID / 128, NTOK / 128, NE), 256, 0, stream>>>(xbf, w1t, b1, ctrl, slot_tok, h);
    gemm2n_k<<<dim3((DIM / 128) * 4, NTOK / 128, NE), 256, 0, stream>>>(h, w2t, b2, ctrl, slot_tok, slot_w, out);
  } else {
    gemm1_k<<<dim3(HID / 128, NTOK / 128, NE), 256, 0, stream>>>(xbf, W1, b1, ctrl, slot_tok, h);
    gemm2_k<<<dim3(DIM / 128, NTOK / 128, NE), 256, 0, stream>>>(h, W2, b2, ctrl, slot_tok, slot_w, out);
  }
}

// Round 5
// 840.455 us; speedup vs baseline: 1.0010x; 1.0010x over previous
//
#include <hip/hip_runtime.h>
#include <math.h>

#define DIM 1024
#define HID 4096
#define NE 8
#define NTOK 4096

typedef short s16x8 __attribute__((ext_vector_type(8)));
typedef float f32x4 __attribute__((ext_vector_type(4)));

// fp32 -> bf16 round-to-nearest-even, bit-level
__device__ __forceinline__ unsigned short f2bf(float f) {
  unsigned int u = __float_as_uint(f);
  u = u + 0x7fffu + ((u >> 16) & 1u);
  return (unsigned short)(u >> 16);
}

__device__ __forceinline__ void gll16(const void* g, void* l) {
  __builtin_amdgcn_global_load_lds(
      (const __attribute__((address_space(1))) unsigned int*)g,
      (__attribute__((address_space(3))) unsigned int*)l, 16, 0, 0);
}

// ---------------- zero: d_out + control ints ----------------
__global__ __launch_bounds__(256) void zero_k(float4* out4, int* ctrl) {
  int i = blockIdx.x * 256 + threadIdx.x;
  out4[i] = make_float4(0.f, 0.f, 0.f, 0.f);
  if (i < 32) ctrl[i] = 0;
}

// ---------------- router: logits, top-2, softmax, x->bf16 ----------------
// ctrl[0..8): counts  ctrl[8..17): offsets  ctrl[20..28): cursors
__global__ __launch_bounds__(256) void router_k(const float* __restrict__ x,
    const float* __restrict__ Wr, const float* __restrict__ br,
    short* __restrict__ xbf, int* __restrict__ ctrl,
    int* __restrict__ sel, float* __restrict__ selw) {
  __shared__ float lred[4 * NE];
  int t = blockIdx.x, tid = threadIdx.x;
  const float* xr = x + (size_t)t * DIM;
  float p[NE];
#pragma unroll
  for (int e = 0; e < NE; ++e) p[e] = 0.f;
#pragma unroll
  for (int it = 0; it < DIM / 256; ++it) {
    int d = it * 256 + tid;
    float xv = xr[d];
    xbf[(size_t)t * DIM + d] = (short)f2bf(xv);
#pragma unroll
    for (int e = 0; e < NE; ++e) p[e] += xv * Wr[d * NE + e];
  }
#pragma unroll
  for (int e = 0; e < NE; ++e) {
    float v = p[e];
#pragma unroll
    for (int off = 32; off > 0; off >>= 1) v += __shfl_down(v, off);
    if ((tid & 63) == 0) lred[(tid >> 6) * NE + e] = v;
  }
  __syncthreads();
  if (tid == 0) {
    float lg[NE];
#pragma unroll
    for (int e = 0; e < NE; ++e)
      lg[e] = lred[e] + lred[NE + e] + lred[2 * NE + e] + lred[3 * NE + e] + br[e];
    int b0 = 0; float v0 = lg[0];
    for (int e = 1; e < NE; ++e) if (lg[e] > v0) { v0 = lg[e]; b0 = e; }
    int b1i = -1; float v1 = -3.4e38f;
    for (int e = 0; e < NE; ++e) if (e != b0 && lg[e] > v1) { v1 = lg[e]; b1i = e; }
    float e1 = expf(v1 - v0);
    float inv = 1.f / (1.f + e1);
    sel[t * 2] = b0; sel[t * 2 + 1] = b1i;
    selw[t * 2] = inv; selw[t * 2 + 1] = e1 * inv;
    atomicAdd(&ctrl[b0], 1); atomicAdd(&ctrl[b1i], 1);
  }
}

// ---------------- scan: offsets ----------------
__global__ void scan_k(int* ctrl) {
  if (threadIdx.x == 0) {
    int o = 0;
#pragma unroll
    for (int e = 0; e < NE; ++e) { ctrl[8 + e] = o; o += ctrl[e]; }
    ctrl[16] = o;
  }
}

// ---------------- build: compact per-expert token lists ----------------
__global__ __launch_bounds__(256) void build_k(const int* __restrict__ sel,
    const float* __restrict__ selw, int* ctrl,
    int* __restrict__ slot_tok, float* __restrict__ slot_w) {
  int t = blockIdx.x * 256 + threadIdx.x;
  if (t >= NTOK) return;
#pragma unroll
  for (int k = 0; k < 2; ++k) {
    int e = sel[t * 2 + k];
    int pos = atomicAdd(&ctrl[20 + e], 1);
    int s = ctrl[8 + e] + pos;
    slot_tok[s] = t;
    slot_w[s] = selw[t * 2 + k];
  }
}

// ---------------- tcvt: fp32 [e][K][N] -> bf16 [e][N][K] (transpose+convert) ----
__global__ __launch_bounds__(256) void tcvt_k(const float* __restrict__ src,
    short* __restrict__ dst, int K, int N) {
  __shared__ __attribute__((aligned(16))) short t[64][72];
  int e = blockIdx.z;
  int n0 = blockIdx.x * 64, k0 = blockIdx.y * 64;
  const float* s = src + (size_t)e * K * N;
  short* d = dst + (size_t)e * N * K;
  int tid = threadIdx.x;
#pragma unroll
  for (int i = 0; i < 4; ++i) {
    int c = tid + i * 256;           // 0..1023
    int row = c >> 4, c4 = c & 15;   // k-row, float4 col chunk
    float4 v = *(const float4*)&s[(size_t)(k0 + row) * N + n0 + c4 * 4];
    t[c4 * 4 + 0][row] = (short)f2bf(v.x);
    t[c4 * 4 + 1][row] = (short)f2bf(v.y);
    t[c4 * 4 + 2][row] = (short)f2bf(v.z);
    t[c4 * 4 + 3][row] = (short)f2bf(v.w);
  }
  __syncthreads();
#pragma unroll
  for (int i = 0; i < 2; ++i) {
    int c = tid + i * 256;           // 0..511
    int n = c >> 3, k8 = c & 7;
    *(s16x8*)&d[(size_t)(n0 + n) * K + k0 + k8 * 8] = *(const s16x8*)&t[n][k8 * 8];
  }
}

// ---- reg-staged pipelined K-step. One barrier/step; loads stay in flight
// (compiler inserts the counted vmcnt before the ds_write use). Cross-wave
// safety = barrier + lgkmcnt only; vmem loads target private regs.
#define BAR_CLUSTER                                                            \
  asm volatile("s_waitcnt lgkmcnt(0)" ::: "memory");                           \
  __builtin_amdgcn_s_barrier();                                                \
  asm volatile("" ::: "memory");                                               \
  __builtin_amdgcn_sched_barrier(0);

#define GBODY(T, NTV, BUFR, BUFW, RS0, RS1, RS2, RS3, RW0, RW1, RW2, RW3)      \
  {                                                                            \
    if ((T) + 2 < (NTV)) {                                                     \
      int off_ = ((T) + 2) * 32;                                               \
      RS0 = *(const s16x8*)(ga[0] + off_);                                     \
      RS1 = *(const s16x8*)(ga[1] + off_);                                     \
      RS2 = *(const s16x8*)(gb[0] + off_);                                     \
      RS3 = *(const s16x8*)(gb[1] + off_);                                     \
    }                                                                          \
    s16x8 aF[4], bF[4];                                                        \
    _Pragma("unroll") for (int i_ = 0; i_ < 4; ++i_)                           \
      aF[i_] = *(const s16x8*)&ldsA[BUFR][(wm * 64 + i_ * 16 + (lane & 15)) * 32 + koff]; \
    _Pragma("unroll") for (int j_ = 0; j_ < 4; ++j_)                           \
      bF[j_] = *(const s16x8*)&ldsB[BUFR][(wn * 64 + j_ * 16 + (lane & 15)) * 32 + koff]; \
    _Pragma("unroll") for (int i_ = 0; i_ < 4; ++i_)                           \
      _Pragma("unroll") for (int j_ = 0; j_ < 4; ++j_)                         \
        acc[i_][j_] = __builtin_amdgcn_mfma_f32_16x16x32_bf16(aF[i_], bF[j_], acc[i_][j_], 0, 0, 0); \
    if ((T) + 1 < (NTV)) {                                                     \
      *(s16x8*)&ldsA[BUFW][lo[0]] = RW0;                                       \
      *(s16x8*)&ldsA[BUFW][lo[1]] = RW1;                                       \
      *(s16x8*)&ldsB[BUFW][lo[0]] = RW2;                                       \
      *(s16x8*)&ldsB[BUFW][lo[1]] = RW3;                                       \
    }                                                                          \
    BAR_CLUSTER                                                                \
  }

#define GPROLOGUE                                                              \
  s16x8 rA0, rA1, rA2, rA3, rB0, rB1, rB2, rB3;                                \
  rA0 = *(const s16x8*)(ga[0]);                                                \
  rA1 = *(const s16x8*)(ga[1]);                                                \
  rA2 = *(const s16x8*)(gb[0]);                                                \
  rA3 = *(const s16x8*)(gb[1]);                                                \
  rB0 = *(const s16x8*)(ga[0] + 32);                                           \
  rB1 = *(const s16x8*)(ga[1] + 32);                                           \
  rB2 = *(const s16x8*)(gb[0] + 32);                                           \
  rB3 = *(const s16x8*)(gb[1] + 32);                                           \
  *(s16x8*)&ldsA[0][lo[0]] = rA0;                                              \
  *(s16x8*)&ldsA[0][lo[1]] = rA1;                                              \
  *(s16x8*)&ldsB[0][lo[0]] = rA2;                                              \
  *(s16x8*)&ldsB[0][lo[1]] = rA3;                                              \
  BAR_CLUSTER

// ---------------- GEMM1: h = gelu(gather(x) @ W1 + b1) ----------------
// 1-D grid 8192, XCD-swizzled; BM=BN=128, BK=32, 4 waves.
__global__ __launch_bounds__(256) void gemm1n_k(const short* __restrict__ xbf,
    const short* __restrict__ w1t, const float* __restrict__ b1,
    const int* __restrict__ ctrl, const int* __restrict__ slot_tok,
    short* __restrict__ h) {
  int bid = blockIdx.x;                       // 8192 total, %8==0
  int swz = (bid & 7) * 1024 + (bid >> 3);    // bijective XCD chunking
  int nx = swz >> 8;                          // 0..31  n-tile
  int e = (swz >> 5) & 7;                     // expert
  int my = swz & 31;                          // m-tile (fastest: share B on XCD)
  int cnt = ctrl[e];
  if (my * 128 >= cnt) return;
  int slot0 = ctrl[8 + e];
  int tid = threadIdx.x, lane = tid & 63;
  int wv = tid >> 6, wm = wv >> 1, wn = wv & 1;
  __shared__ __attribute__((aligned(16))) short ldsA[2][128 * 32];
  __shared__ __attribute__((aligned(16))) short ldsB[2][128 * 32];

  const short* ga[2]; const short* gb[2]; int lo[2];
#pragma unroll
  for (int i = 0; i < 2; ++i) {
    int c = tid + i * 256;
    int row = c >> 2;
    int cs = (c & 3) ^ (row & 3);    // source chunk pre-swizzle (involution)
    int srow = min(my * 128 + row, cnt - 1);
    ga[i] = xbf + (size_t)slot_tok[slot0 + srow] * DIM + cs * 8;
    gb[i] = w1t + ((size_t)e * HID + nx * 128 + row) * DIM + cs * 8;
    lo[i] = c * 8;
  }
  int koff = ((lane >> 4) ^ (lane & 3)) * 8;  // swizzled read chunk

  f32x4 acc[4][4];
#pragma unroll
  for (int i = 0; i < 4; ++i)
#pragma unroll
    for (int j = 0; j < 4; ++j) acc[i][j] = (f32x4){0.f, 0.f, 0.f, 0.f};

  GPROLOGUE
  const int NT = DIM / 32;  // 32, even
  for (int t = 0; t < NT; t += 2) {
    GBODY(t,     NT, 0, 1, rA0, rA1, rA2, rA3, rB0, rB1, rB2, rB3)
    GBODY(t + 1, NT, 1, 0, rB0, rB1, rB2, rB3, rA0, rA1, rA2, rA3)
  }

#pragma unroll
  for (int i = 0; i < 4; ++i) {
#pragma unroll
    for (int r = 0; r < 4; ++r) {
      int row_l = wm * 64 + i * 16 + (lane >> 4) * 4 + r;
      int grow = my * 128 + row_l;
      if (grow < cnt) {
#pragma unroll
        for (int j = 0; j < 4; ++j) {
          int col = nx * 128 + wn * 64 + j * 16 + (lane & 15);
          float z = acc[i][j][r] + b1[e * HID + col];
          float g = 0.5f * z * (1.f + erff(z * 0.70710678118f));
          h[(size_t)(slot0 + grow) * HID + col] = (short)f2bf(g);
        }
      }
    }
  }
}

// ---------------- GEMM2: out += w * (h @ W2 + b2), K-split x2 ----------------
__global__ __launch_bounds__(256) void gemm2n_k(const short* __restrict__ h,
    const short* __restrict__ w2t, const float* __restrict__ b2,
    const int* __restrict__ ctrl, const int* __restrict__ slot_tok,
    const float* __restrict__ slot_w, float* __restrict__ out) {
  int bid = blockIdx.x;                       // 4096 total, %8==0
  int swz = (bid & 7) * 512 + (bid >> 3);
  int kc = swz >> 11;                         // 0..1
  int nx = (swz >> 8) & 7;                    // 0..7
  int e = (swz >> 5) & 7;
  int my = swz & 31;
  int cnt = ctrl[e];
  if (my * 128 >= cnt) return;
  int slot0 = ctrl[8 + e];
  int tid = threadIdx.x, lane = tid & 63;
  int wv = tid >> 6, wm = wv >> 1, wn = wv & 1;
  __shared__ __attribute__((aligned(16))) short ldsA[2][128 * 32];
  __shared__ __attribute__((aligned(16))) short ldsB[2][128 * 32];
  __shared__ int stok[128];
  __shared__ float swt[128];
  if (tid < 128) {
    int srow = min(my * 128 + tid, cnt - 1);
    stok[tid] = slot_tok[slot0 + srow];
    swt[tid] = slot_w[slot0 + srow];
  }
  int k0 = kc * (HID / 2);
  const short* ga[2]; const short* gb[2]; int lo[2];
#pragma unroll
  for (int i = 0; i < 2; ++i) {
    int c = tid + i * 256;
    int row = c >> 2;
    int cs = (c & 3) ^ (row & 3);
    int srow = min(my * 128 + row, cnt - 1);
    ga[i] = h + (size_t)(slot0 + srow) * HID + k0 + cs * 8;
    gb[i] = w2t + ((size_t)e * DIM + nx * 128 + row) * HID + k0 + cs * 8;
    lo[i] = c * 8;
  }
  int koff = ((lane >> 4) ^ (lane & 3)) * 8;

  f32x4 acc[4][4];
#pragma unroll
  for (int i = 0; i < 4; ++i)
#pragma unroll
    for (int j = 0; j < 4; ++j) acc[i][j] = (f32x4){0.f, 0.f, 0.f, 0.f};

  GPROLOGUE
  const int NT = (HID / 2) / 32;  // 64, even
  for (int t = 0; t < NT; t += 2) {
    GBODY(t,     NT, 0, 1, rA0, rA1, rA2, rA3, rB0, rB1, rB2, rB3)
    GBODY(t + 1, NT, 1, 0, rB0, rB1, rB2, rB3, rA0, rA1, rA2, rA3)
  }

#pragma unroll
  for (int i = 0; i < 4; ++i) {
#pragma unroll
    for (int r = 0; r < 4; ++r) {
      int row_l = wm * 64 + i * 16 + (lane >> 4) * 4 + r;
      int grow = my * 128 + row_l;
      if (grow < cnt) {
        int tok = stok[row_l];
        float wrow = swt[row_l];
#pragma unroll
        for (int j = 0; j < 4; ++j) {
          int col = nx * 128 + wn * 64 + j * 16 + (lane & 15);
          float y = acc[i][j][r];
          if (kc == 0) y += b2[e * DIM + col];
          unsafeAtomicAdd(&out[(size_t)tok * DIM + col], wrow * y);
        }
      }
    }
  }
}

// ================= fallback (round-2, passed) GEMMs: used if ws too small ======
__global__ __launch_bounds__(256) void gemm1_k(const short* __restrict__ xbf,
    const float* __restrict__ W1, const float* __restrict__ b1,
    const int* __restrict__ ctrl, const int* __restrict__ slot_tok,
    short* __restrict__ h) {
  int e = blockIdx.z, my = blockIdx.y, bx = blockIdx.x;
  int cnt = ctrl[e];
  if (my * 128 >= cnt) return;
  int slot0 = ctrl[8 + e];
  int tid = threadIdx.x, lane = tid & 63;
  int wv = tid >> 6, wm = wv >> 1, wn = wv & 1;
  __shared__ __attribute__((aligned(16))) short ldsA[128 * 32];
  __shared__ __attribute__((aligned(16))) short ldsB[128 * 40];
  const short* ap[2]; short* la[2];
#pragma unroll
  for (int i = 0; i < 2; ++i) {
    int c = tid + i * 256;
    int row = c >> 2;
    int srow = min(my * 128 + row, cnt - 1);
    int tok = slot_tok[slot0 + srow];
    ap[i] = xbf + (size_t)tok * DIM + (c & 3) * 8;
    la[i] = &ldsA[c * 8];
  }
  int n0 = (tid & 63) * 2;
  int kg = tid >> 6;
  const float* bp = W1 + ((size_t)e * DIM + kg * 8) * HID + bx * 128 + n0;
  short* lb0 = &ldsB[(n0) * 40 + kg * 8];
  short* lb1 = &ldsB[(n0 + 1) * 40 + kg * 8];
  f32x4 acc[4][4];
#pragma unroll
  for (int i = 0; i < 4; ++i)
#pragma unroll
    for (int j = 0; j < 4; ++j) acc[i][j] = (f32x4){0.f, 0.f, 0.f, 0.f};
#pragma unroll 2
  for (int kt = 0; kt < DIM / 32; ++kt) {
    float2 fv[8];
#pragma unroll
    for (int kk = 0; kk < 8; ++kk) fv[kk] = *(const float2*)&bp[(size_t)kk * HID];
    __syncthreads();
    gll16(ap[0], la[0]); gll16(ap[1], la[1]);
    s16x8 v0, v1;
#pragma unroll
    for (int kk = 0; kk < 8; ++kk) { v0[kk] = (short)f2bf(fv[kk].x); v1[kk] = (short)f2bf(fv[kk].y); }
    *(s16x8*)lb0 = v0; *(s16x8*)lb1 = v1;
    asm volatile("s_waitcnt vmcnt(0)" ::: "memory");
    __syncthreads();
    s16x8 aF[4], bF[4];
#pragma unroll
    for (int i = 0; i < 4; ++i)
      aF[i] = *(const s16x8*)&ldsA[(wm * 64 + i * 16 + (lane & 15)) * 32 + (lane >> 4) * 8];
#pragma unroll
    for (int j = 0; j < 4; ++j)
      bF[j] = *(const s16x8*)&ldsB[(wn * 64 + j * 16 + (lane & 15)) * 40 + (lane >> 4) * 8];
#pragma unroll
    for (int i = 0; i < 4; ++i)
#pragma unroll
      for (int j = 0; j < 4; ++j)
        acc[i][j] = __builtin_amdgcn_mfma_f32_16x16x32_bf16(aF[i], bF[j], acc[i][j], 0, 0, 0);
    ap[0] += 32; ap[1] += 32; bp += (size_t)32 * HID;
  }
#pragma unroll
  for (int i = 0; i < 4; ++i)
#pragma unroll
    for (int r = 0; r < 4; ++r) {
      int row_l = wm * 64 + i * 16 + (lane >> 4) * 4 + r;
      int grow = my * 128 + row_l;
      if (grow < cnt)
#pragma unroll
        for (int j = 0; j < 4; ++j) {
          int col = bx * 128 + wn * 64 + j * 16 + (lane & 15);
          float z = acc[i][j][r] + b1[e * HID + col];
          float g = 0.5f * z * (1.f + erff(z * 0.70710678118f));
          h[(size_t)(slot0 + grow) * HID + col] = (short)f2bf(g);
        }
    }
}

__global__ __launch_bounds__(256) void gemm2_k(const short* __restrict__ h,
    const float* __restrict__ W2, const float* __restrict__ b2,
    const int* __restrict__ ctrl, const int* __restrict__ slot_tok,
    const float* __restrict__ slot_w, float* __restrict__ out) {
  int e = blockIdx.z, my = blockIdx.y, bx = blockIdx.x;
  int cnt = ctrl[e];
  if (my * 128 >= cnt) return;
  int slot0 = ctrl[8 + e];
  int tid = threadIdx.x, lane = tid & 63;
  int wv = tid >> 6, wm = wv >> 1, wn = wv & 1;
  __shared__ __attribute__((aligned(16))) short ldsA[128 * 32];
  __shared__ __attribute__((aligned(16))) short ldsB[128 * 40];
  __shared__ int stok[128];
  __shared__ float swt[128];
  if (tid < 128) {
    int srow = min(my * 128 + tid, cnt - 1);
    stok[tid] = slot_tok[slot0 + srow];
    swt[tid] = slot_w[slot0 + srow];
  }
  const short* ap[2]; short* la[2];
#pragma unroll
  for (int i = 0; i < 2; ++i) {
    int c = tid + i * 256;
    int row = c >> 2;
    int srow = min(my * 128 + row, cnt - 1);
    ap[i] = h + (size_t)(slot0 + srow) * HID + (c & 3) * 8;
    la[i] = &ldsA[c * 8];
  }
  int n0 = (tid & 63) * 2;
  int kg = tid >> 6;
  const float* bp = W2 + ((size_t)e * HID + kg * 8) * DIM + bx * 128 + n0;
  short* lb0 = &ldsB[(n0) * 40 + kg * 8];
  short* lb1 = &ldsB[(n0 + 1) * 40 + kg * 8];
  f32x4 acc[4][4];
#pragma unroll
  for (int i = 0; i < 4; ++i)
#pragma unroll
    for (int j = 0; j < 4; ++j) acc[i][j] = (f32x4){0.f, 0.f, 0.f, 0.f};
#pragma unroll 2
  for (int kt = 0; kt < HID / 32; ++kt) {
    float2 fv[8];
#pragma unroll
    for (int kk = 0; kk < 8; ++kk) fv[kk] = *(const float2*)&bp[(size_t)kk * DIM];
    __syncthreads();
    gll16(ap[0], la[0]); gll16(ap[1], la[1]);
    s16x8 v0, v1;
#pragma unroll
    for (int kk = 0; kk < 8; ++kk) { v0[kk] = (short)f2bf(fv[kk].x); v1[kk] = (short)f2bf(fv[kk].y); }
    *(s16x8*)lb0 = v0; *(s16x8*)lb1 = v1;
    asm volatile("s_waitcnt vmcnt(0)" ::: "memory");
    __syncthreads();
    s16x8 aF[4], bF[4];
#pragma unroll
    for (int i = 0; i < 4; ++i)
      aF[i] = *(const s16x8*)&ldsA[(wm * 64 + i * 16 + (lane & 15)) * 32 + (lane >> 4) * 8];
#pragma unroll
    for (int j = 0; j < 4; ++j)
      bF[j] = *(const s16x8*)&ldsB[(wn * 64 + j * 16 + (lane & 15)) * 40 + (lane >> 4) * 8];
#pragma unroll
    for (int i = 0; i < 4; ++i)
#pragma unroll
      for (int j = 0; j < 4; ++j)
        acc[i][j] = __builtin_amdgcn_mfma_f32_16x16x32_bf16(aF[i], bF[j], acc[i][j], 0, 0, 0);
    ap[0] += 32; ap[1] += 32; bp += (size_t)32 * DIM;
  }
#pragma unroll
  for (int i = 0; i < 4; ++i)
#pragma unroll
    for (int r = 0; r < 4; ++r) {
      int row_l = wm * 64 + i * 16 + (lane >> 4) * 4 + r;
      int grow = my * 128 + row_l;
      if (grow < cnt) {
        int tok = stok[row_l];
        float wrow = swt[row_l];
#pragma unroll
        for (int j = 0; j < 4; ++j) {
          int col = bx * 128 + wn * 64 + j * 16 + (lane & 15);
          float y = acc[i][j][r] + b2[e * DIM + col];
          unsafeAtomicAdd(&out[(size_t)tok * DIM + col], wrow * y);
        }
      }
    }
}

extern "C" void kernel_launch(void* const* d_in, const int* in_sizes, int n_in,
                              void* d_out, int out_size, void* d_ws, size_t ws_size,
                              hipStream_t stream) {
  const float* x  = (const float*)d_in[0];
  const float* Wr = (const float*)d_in[1];
  const float* br = (const float*)d_in[2];
  const float* W1 = (const float*)d_in[3];
  const float* b1 = (const float*)d_in[4];
  const float* W2 = (const float*)d_in[5];
  const float* b2 = (const float*)d_in[6];
  float* out = (float*)d_out;

  char* ws = (char*)d_ws;
  const size_t MiB = 1024 * 1024;
  int*   ctrl     = (int*)(ws);
  int*   sel      = (int*)(ws + 1024);
  float* selw     = (float*)(ws + 33792);
  int*   slot_tok = (int*)(ws + 66560);
  float* slot_w   = (float*)(ws + 99328);
  short* xbf      = (short*)(ws + 1 * MiB);    // 8 MiB
  short* h        = (short*)(ws + 16 * MiB);   // 64 MiB
  short* w1t      = (short*)(ws + 80 * MiB);   // 64 MiB  [e][HID][DIM] bf16
  short* w2t      = (short*)(ws + 144 * MiB);  // 64 MiB  [e][DIM][HID] bf16
  bool fat = ws_size >= 208 * MiB;

  zero_k<<<(NTOK * DIM / 4) / 256, 256, 0, stream>>>((float4*)out, ctrl);
  router_k<<<NTOK, 256, 0, stream>>>(x, Wr, br, xbf, ctrl, sel, selw);
  scan_k<<<1, 64, 0, stream>>>(ctrl);
  build_k<<<NTOK / 256, 256, 0, stream>>>(sel, selw, ctrl, slot_tok, slot_w);
  if (fat) {
    tcvt_k<<<dim3(HID / 64, DIM / 64, NE), 256, 0, stream>>>(W1, w1t, DIM, HID);
    tcvt_k<<<dim3(DIM / 64, HID / 64, NE), 256, 0, stream>>>(W2, w2t, HID, DIM);
    gemm1n_k<<<32 * 32 * NE, 256, 0, stream>>>(xbf, w1t, b1, ctrl, slot_tok, h);
    gemm2n_k<<<8 * 32 * NE * 2, 256, 0, stream>>>(h, w2t, b2, ctrl, slot_tok, slot_w, out);
  } else {
    gemm1_k<<<dim3(HID / 128, NTOK / 128, NE), 256, 0, stream>>>(xbf, W1, b1, ctrl, slot_tok, h);
    gemm2_k<<<dim3(DIM / 128, NTOK / 128, NE), 256, 0, stream>>>(h, W2, b2, ctrl, slot_tok, slot_w, out);
  }
}

// Round 8
// 818.745 us; speedup vs baseline: 1.0276x; 1.0265x over previous
//
#include <hip/hip_runtime.h>
#include <math.h>

#define DIM 1024
#define HID 4096
#define NE 8
#define NTOK 4096

typedef short s16x8 __attribute__((ext_vector_type(8)));
typedef float f32x4 __attribute__((ext_vector_type(4)));

// fp32 -> bf16 round-to-nearest-even, bit-level
__device__ __forceinline__ unsigned short f2bf(float f) {
  unsigned int u = __float_as_uint(f);
  u = u + 0x7fffu + ((u >> 16) & 1u);
  return (unsigned short)(u >> 16);
}

__device__ __forceinline__ void gll16(const void* g, void* l) {
  __builtin_amdgcn_global_load_lds(
      (const __attribute__((address_space(1))) unsigned int*)g,
      (__attribute__((address_space(3))) unsigned int*)l, 16, 0, 0);
}

// ---------------- zero: d_out + control ints ----------------
__global__ __launch_bounds__(256) void zero_k(float4* out4, int* ctrl) {
  int i = blockIdx.x * 256 + threadIdx.x;
  out4[i] = make_float4(0.f, 0.f, 0.f, 0.f);
  if (i < 32) ctrl[i] = 0;
}

// ---------------- router: logits, top-2, softmax, x->bf16 ----------------
// ctrl[0..8): counts  ctrl[8..17): offsets  ctrl[20..28): cursors
__global__ __launch_bounds__(256) void router_k(const float* __restrict__ x,
    const float* __restrict__ Wr, const float* __restrict__ br,
    short* __restrict__ xbf, int* __restrict__ ctrl,
    int* __restrict__ sel, float* __restrict__ selw) {
  __shared__ float lred[4 * NE];
  int t = blockIdx.x, tid = threadIdx.x;
  const float* xr = x + (size_t)t * DIM;
  float p[NE];
#pragma unroll
  for (int e = 0; e < NE; ++e) p[e] = 0.f;
#pragma unroll
  for (int it = 0; it < DIM / 256; ++it) {
    int d = it * 256 + tid;
    float xv = xr[d];
    xbf[(size_t)t * DIM + d] = (short)f2bf(xv);
#pragma unroll
    for (int e = 0; e < NE; ++e) p[e] += xv * Wr[d * NE + e];
  }
#pragma unroll
  for (int e = 0; e < NE; ++e) {
    float v = p[e];
#pragma unroll
    for (int off = 32; off > 0; off >>= 1) v += __shfl_down(v, off);
    if ((tid & 63) == 0) lred[(tid >> 6) * NE + e] = v;
  }
  __syncthreads();
  if (tid == 0) {
    float lg[NE];
#pragma unroll
    for (int e = 0; e < NE; ++e)
      lg[e] = lred[e] + lred[NE + e] + lred[2 * NE + e] + lred[3 * NE + e] + br[e];
    int b0 = 0; float v0 = lg[0];
    for (int e = 1; e < NE; ++e) if (lg[e] > v0) { v0 = lg[e]; b0 = e; }
    int b1i = -1; float v1 = -3.4e38f;
    for (int e = 0; e < NE; ++e) if (e != b0 && lg[e] > v1) { v1 = lg[e]; b1i = e; }
    float e1 = expf(v1 - v0);
    float inv = 1.f / (1.f + e1);
    sel[t * 2] = b0; sel[t * 2 + 1] = b1i;
    selw[t * 2] = inv; selw[t * 2 + 1] = e1 * inv;
    atomicAdd(&ctrl[b0], 1); atomicAdd(&ctrl[b1i], 1);
  }
}

// ---------------- scan: offsets ----------------
__global__ void scan_k(int* ctrl) {
  if (threadIdx.x == 0) {
    int o = 0;
#pragma unroll
    for (int e = 0; e < NE; ++e) { ctrl[8 + e] = o; o += ctrl[e]; }
    ctrl[16] = o;
  }
}

// ---------------- build: compact per-expert token lists ----------------
__global__ __launch_bounds__(256) void build_k(const int* __restrict__ sel,
    const float* __restrict__ selw, int* ctrl,
    int* __restrict__ slot_tok, float* __restrict__ slot_w) {
  int t = blockIdx.x * 256 + threadIdx.x;
  if (t >= NTOK) return;
#pragma unroll
  for (int k = 0; k < 2; ++k) {
    int e = sel[t * 2 + k];
    int pos = atomicAdd(&ctrl[20 + e], 1);
    int s = ctrl[8 + e] + pos;
    slot_tok[s] = t;
    slot_w[s] = selw[t * 2 + k];
  }
}

// ---------------- tcvt: fp32 [e][K][N] -> bf16 [e][N][K] (transpose+convert) ----
__global__ __launch_bounds__(256) void tcvt_k(const float* __restrict__ src,
    short* __restrict__ dst, int K, int N) {
  __shared__ __attribute__((aligned(16))) short t[64][72];
  int e = blockIdx.z;
  int n0 = blockIdx.x * 64, k0 = blockIdx.y * 64;
  const float* s = src + (size_t)e * K * N;
  short* d = dst + (size_t)e * N * K;
  int tid = threadIdx.x;
#pragma unroll
  for (int i = 0; i < 4; ++i) {
    int c = tid + i * 256;           // 0..1023
    int row = c >> 4, c4 = c & 15;   // k-row, float4 col chunk
    float4 v = *(const float4*)&s[(size_t)(k0 + row) * N + n0 + c4 * 4];
    t[c4 * 4 + 0][row] = (short)f2bf(v.x);
    t[c4 * 4 + 1][row] = (short)f2bf(v.y);
    t[c4 * 4 + 2][row] = (short)f2bf(v.z);
    t[c4 * 4 + 3][row] = (short)f2bf(v.w);
  }
  __syncthreads();
#pragma unroll
  for (int i = 0; i < 2; ++i) {
    int c = tid + i * 256;           // 0..511
    int n = c >> 3, k8 = c & 7;
    *(s16x8*)&d[(size_t)(n0 + n) * K + k0 + k8 * 8] = *(const s16x8*)&t[n][k8 * 8];
  }
}

// ---- reg-staged pipeline, 2-step load->write slack ----
// Step t: (1) ds_write tile t+1 into buf[(t+1)&1] from set[(t+1)&1]
//             (regs loaded at step t-2 -> ~2 steps of global-load slack),
//         (2) reload freed set with tile t+3,
//         (3) ds_read buf[t&1] + 16 MFMA (covers the write's lgkm drain),
//         (4) lgkmcnt(0) + barrier.
// Cross-wave safety: single barrier + lgkmcnt(0); vmem loads target private
// regs, so no cross-wave vmcnt counting anywhere.
#define BAR_SYNC                                                               \
  asm volatile("s_waitcnt lgkmcnt(0)" ::: "memory");                           \
  __builtin_amdgcn_s_barrier();                                                \
  asm volatile("" ::: "memory");                                               \
  __builtin_amdgcn_sched_barrier(0);

#define PSTEP(T, NTV, BUFW, BUFR, W0, W1, W2, W3)                              \
  {                                                                            \
    if ((T) + 1 < (NTV)) {                                                     \
      *(s16x8*)&ldsA[BUFW][lo[0]] = W0;                                        \
      *(s16x8*)&ldsA[BUFW][lo[1]] = W1;                                        \
      *(s16x8*)&ldsB[BUFW][lo[0]] = W2;                                        \
      *(s16x8*)&ldsB[BUFW][lo[1]] = W3;                                        \
    }                                                                          \
    if ((T) + 3 < (NTV)) {                                                     \
      int off_ = ((T) + 3) * 32;                                               \
      W0 = *(const s16x8*)(ga[0] + off_);                                      \
      W1 = *(const s16x8*)(ga[1] + off_);                                      \
      W2 = *(const s16x8*)(gb[0] + off_);                                      \
      W3 = *(const s16x8*)(gb[1] + off_);                                      \
    }                                                                          \
    s16x8 aF[4], bF[4];                                                        \
    _Pragma("unroll") for (int i_ = 0; i_ < 4; ++i_)                           \
      aF[i_] = *(const s16x8*)&ldsA[BUFR][(wm * 64 + i_ * 16 + (lane & 15)) * 32 + koff]; \
    _Pragma("unroll") for (int j_ = 0; j_ < 4; ++j_)                           \
      bF[j_] = *(const s16x8*)&ldsB[BUFR][(wn * 64 + j_ * 16 + (lane & 15)) * 32 + koff]; \
    _Pragma("unroll") for (int i_ = 0; i_ < 4; ++i_)                           \
      _Pragma("unroll") for (int j_ = 0; j_ < 4; ++j_)                         \
        acc[i_][j_] = __builtin_amdgcn_mfma_f32_16x16x32_bf16(aF[i_], bF[j_], acc[i_][j_], 0, 0, 0); \
    BAR_SYNC                                                                   \
  }

// Prologue: tile0 -> setA -> buf0; tile1 -> setB (written at step 0);
// tile2 -> setA (written at step 1).
#define GPROLOGUE                                                              \
  s16x8 sA0, sA1, sA2, sA3, sB0, sB1, sB2, sB3;                                \
  sA0 = *(const s16x8*)(ga[0]);                                                \
  sA1 = *(const s16x8*)(ga[1]);                                                \
  sA2 = *(const s16x8*)(gb[0]);                                                \
  sA3 = *(const s16x8*)(gb[1]);                                                \
  sB0 = *(const s16x8*)(ga[0] + 32);                                           \
  sB1 = *(const s16x8*)(ga[1] + 32);                                           \
  sB2 = *(const s16x8*)(gb[0] + 32);                                           \
  sB3 = *(const s16x8*)(gb[1] + 32);                                           \
  *(s16x8*)&ldsA[0][lo[0]] = sA0;                                              \
  *(s16x8*)&ldsA[0][lo[1]] = sA1;                                              \
  *(s16x8*)&ldsB[0][lo[0]] = sA2;                                              \
  *(s16x8*)&ldsB[0][lo[1]] = sA3;                                              \
  sA0 = *(const s16x8*)(ga[0] + 64);                                           \
  sA1 = *(const s16x8*)(ga[1] + 64);                                           \
  sA2 = *(const s16x8*)(gb[0] + 64);                                           \
  sA3 = *(const s16x8*)(gb[1] + 64);                                           \
  BAR_SYNC

// ---------------- GEMM1: h = gelu(gather(x) @ W1 + b1) ----------------
// 1-D grid 8192, XCD-swizzled; BM=BN=128, BK=32, 4 waves.
__global__ __launch_bounds__(256) void gemm1n_k(const short* __restrict__ xbf,
    const short* __restrict__ w1t, const float* __restrict__ b1,
    const int* __restrict__ ctrl, const int* __restrict__ slot_tok,
    short* __restrict__ h) {
  int bid = blockIdx.x;                       // 8192 total, %8==0
  int swz = (bid & 7) * 1024 + (bid >> 3);    // bijective XCD chunking
  int nx = swz >> 8;                          // 0..31  n-tile
  int e = (swz >> 5) & 7;                     // expert
  int my = swz & 31;                          // m-tile (fastest: share B on XCD)
  int cnt = ctrl[e];
  if (my * 128 >= cnt) return;
  int slot0 = ctrl[8 + e];
  int tid = threadIdx.x, lane = tid & 63;
  int wv = tid >> 6, wm = wv >> 1, wn = wv & 1;
  __shared__ __attribute__((aligned(16))) short ldsA[2][128 * 32];
  __shared__ __attribute__((aligned(16))) short ldsB[2][128 * 32];

  const short* ga[2]; const short* gb[2]; int lo[2];
#pragma unroll
  for (int i = 0; i < 2; ++i) {
    int c = tid + i * 256;
    int row = c >> 2;
    int cs = (c & 3) ^ (row & 3);    // source chunk pre-swizzle (involution)
    int srow = min(my * 128 + row, cnt - 1);
    ga[i] = xbf + (size_t)slot_tok[slot0 + srow] * DIM + cs * 8;
    gb[i] = w1t + ((size_t)e * HID + nx * 128 + row) * DIM + cs * 8;
    lo[i] = c * 8;
  }
  int koff = ((lane >> 4) ^ (lane & 3)) * 8;  // swizzled read chunk

  f32x4 acc[4][4];
#pragma unroll
  for (int i = 0; i < 4; ++i)
#pragma unroll
    for (int j = 0; j < 4; ++j) acc[i][j] = (f32x4){0.f, 0.f, 0.f, 0.f};

  GPROLOGUE
  const int NT = DIM / 32;  // 32, even
  for (int t = 0; t < NT; t += 2) {
    PSTEP(t,     NT, 1, 0, sB0, sB1, sB2, sB3)   // write tile t+1, read buf0
    PSTEP(t + 1, NT, 0, 1, sA0, sA1, sA2, sA3)   // write tile t+2, read buf1
  }

#pragma unroll
  for (int i = 0; i < 4; ++i) {
#pragma unroll
    for (int r = 0; r < 4; ++r) {
      int row_l = wm * 64 + i * 16 + (lane >> 4) * 4 + r;
      int grow = my * 128 + row_l;
      if (grow < cnt) {
#pragma unroll
        for (int j = 0; j < 4; ++j) {
          int col = nx * 128 + wn * 64 + j * 16 + (lane & 15);
          float z = acc[i][j][r] + b1[e * HID + col];
          float g = 0.5f * z * (1.f + erff(z * 0.70710678118f));
          h[(size_t)(slot0 + grow) * HID + col] = (short)f2bf(g);
        }
      }
    }
  }
}

// ---------------- GEMM2: out += w * (h @ W2 + b2), K-split x2 ----------------
__global__ __launch_bounds__(256) void gemm2n_k(const short* __restrict__ h,
    const short* __restrict__ w2t, const float* __restrict__ b2,
    const int* __restrict__ ctrl, const int* __restrict__ slot_tok,
    const float* __restrict__ slot_w, float* __restrict__ out) {
  int bid = blockIdx.x;                       // 4096 total, %8==0
  int swz = (bid & 7) * 512 + (bid >> 3);
  int kc = swz >> 11;                         // 0..1
  int nx = (swz >> 8) & 7;                    // 0..7
  int e = (swz >> 5) & 7;
  int my = swz & 31;
  int cnt = ctrl[e];
  if (my * 128 >= cnt) return;
  int slot0 = ctrl[8 + e];
  int tid = threadIdx.x, lane = tid & 63;
  int wv = tid >> 6, wm = wv >> 1, wn = wv & 1;
  __shared__ __attribute__((aligned(16))) short ldsA[2][128 * 32];
  __shared__ __attribute__((aligned(16))) short ldsB[2][128 * 32];
  __shared__ int stok[128];
  __shared__ float swt[128];
  if (tid < 128) {
    int srow = min(my * 128 + tid, cnt - 1);
    stok[tid] = slot_tok[slot0 + srow];
    swt[tid] = slot_w[slot0 + srow];
  }
  int k0 = kc * (HID / 2);
  const short* ga[2]; const short* gb[2]; int lo[2];
#pragma unroll
  for (int i = 0; i < 2; ++i) {
    int c = tid + i * 256;
    int row = c >> 2;
    int cs = (c & 3) ^ (row & 3);
    int srow = min(my * 128 + row, cnt - 1);
    ga[i] = h + (size_t)(slot0 + srow) * HID + k0 + cs * 8;
    gb[i] = w2t + ((size_t)e * DIM + nx * 128 + row) * HID + k0 + cs * 8;
    lo[i] = c * 8;
  }
  int koff = ((lane >> 4) ^ (lane & 3)) * 8;

  f32x4 acc[4][4];
#pragma unroll
  for (int i = 0; i < 4; ++i)
#pragma unroll
    for (int j = 0; j < 4; ++j) acc[i][j] = (f32x4){0.f, 0.f, 0.f, 0.f};

  GPROLOGUE
  const int NT = (HID / 2) / 32;  // 64, even
  for (int t = 0; t < NT; t += 2) {
    PSTEP(t,     NT, 1, 0, sB0, sB1, sB2, sB3)
    PSTEP(t + 1, NT, 0, 1, sA0, sA1, sA2, sA3)
  }

#pragma unroll
  for (int i = 0; i < 4; ++i) {
#pragma unroll
    for (int r = 0; r < 4; ++r) {
      int row_l = wm * 64 + i * 16 + (lane >> 4) * 4 + r;
      int grow = my * 128 + row_l;
      if (grow < cnt) {
        int tok = stok[row_l];
        float wrow = swt[row_l];
#pragma unroll
        for (int j = 0; j < 4; ++j) {
          int col = nx * 128 + wn * 64 + j * 16 + (lane & 15);
          float y = acc[i][j][r];
          if (kc == 0) y += b2[e * DIM + col];
          unsafeAtomicAdd(&out[(size_t)tok * DIM + col], wrow * y);
        }
      }
    }
  }
}

// ================= fallback (round-2, passed) GEMMs: used if ws too small ======
__global__ __launch_bounds__(256) void gemm1_k(const short* __restrict__ xbf,
    const float* __restrict__ W1, const float* __restrict__ b1,
    const int* __restrict__ ctrl, const int* __restrict__ slot_tok,
    short* __restrict__ h) {
  int e = blockIdx.z, my = blockIdx.y, bx = blockIdx.x;
  int cnt = ctrl[e];
  if (my * 128 >= cnt) return;
  int slot0 = ctrl[8 + e];
  int tid = threadIdx.x, lane = tid & 63;
  int wv = tid >> 6, wm = wv >> 1, wn = wv & 1;
  __shared__ __attribute__((aligned(16))) short ldsA[128 * 32];
  __shared__ __attribute__((aligned(16))) short ldsB[128 * 40];
  const short* ap[2]; short* la[2];
#pragma unroll
  for (int i = 0; i < 2; ++i) {
    int c = tid + i * 256;
    int row = c >> 2;
    int srow = min(my * 128 + row, cnt - 1);
    int tok = slot_tok[slot0 + srow];
    ap[i] = xbf + (size_t)tok * DIM + (c & 3) * 8;
    la[i] = &ldsA[c * 8];
  }
  int n0 = (tid & 63) * 2;
  int kg = tid >> 6;
  const float* bp = W1 + ((size_t)e * DIM + kg * 8) * HID + bx * 128 + n0;
  short* lb0 = &ldsB[(n0) * 40 + kg * 8];
  short* lb1 = &ldsB[(n0 + 1) * 40 + kg * 8];
  f32x4 acc[4][4];
#pragma unroll
  for (int i = 0; i < 4; ++i)
#pragma unroll
    for (int j = 0; j < 4; ++j) acc[i][j] = (f32x4){0.f, 0.f, 0.f, 0.f};
#pragma unroll 2
  for (int kt = 0; kt < DIM / 32; ++kt) {
    float2 fv[8];
#pragma unroll
    for (int kk = 0; kk < 8; ++kk) fv[kk] = *(const float2*)&bp[(size_t)kk * HID];
    __syncthreads();
    gll16(ap[0], la[0]); gll16(ap[1], la[1]);
    s16x8 v0, v1;
#pragma unroll
    for (int kk = 0; kk < 8; ++kk) { v0[kk] = (short)f2bf(fv[kk].x); v1[kk] = (short)f2bf(fv[kk].y); }
    *(s16x8*)lb0 = v0; *(s16x8*)lb1 = v1;
    asm volatile("s_waitcnt vmcnt(0)" ::: "memory");
    __syncthreads();
    s16x8 aF[4], bF[4];
#pragma unroll
    for (int i = 0; i < 4; ++i)
      aF[i] = *(const s16x8*)&ldsA[(wm * 64 + i * 16 + (lane & 15)) * 32 + (lane >> 4) * 8];
#pragma unroll
    for (int j = 0; j < 4; ++j)
      bF[j] = *(const s16x8*)&ldsB[(wn * 64 + j * 16 + (lane & 15)) * 40 + (lane >> 4) * 8];
#pragma unroll
    for (int i = 0; i < 4; ++i)
#pragma unroll
      for (int j = 0; j < 4; ++j)
        acc[i][j] = __builtin_amdgcn_mfma_f32_16x16x32_bf16(aF[i], bF[j], acc[i][j], 0, 0, 0);
    ap[0] += 32; ap[1] += 32; bp += (size_t)32 * HID;
  }
#pragma unroll
  for (int i = 0; i < 4; ++i)
#pragma unroll
    for (int r = 0; r < 4; ++r) {
      int row_l = wm * 64 + i * 16 + (lane >> 4) * 4 + r;
      int grow = my * 128 + row_l;
      if (grow < cnt)
#pragma unroll
        for (int j = 0; j < 4; ++j) {
          int col = bx * 128 + wn * 64 + j * 16 + (lane & 15);
          float z = acc[i][j][r] + b1[e * HID + col];
          float g = 0.5f * z * (1.f + erff(z * 0.70710678118f));
          h[(size_t)(slot0 + grow) * HID + col] = (short)f2bf(g);
        }
    }
}

__global__ __launch_bounds__(256) void gemm2_k(const short* __restrict__ h,
    const float* __restrict__ W2, const float* __restrict__ b2,
    const int* __restrict__ ctrl, const int* __restrict__ slot_tok,
    const float* __restrict__ slot_w, float* __restrict__ out) {
  int e = blockIdx.z, my = blockIdx.y, bx = blockIdx.x;
  int cnt = ctrl[e];
  if (my * 128 >= cnt) return;
  int slot0 = ctrl[8 + e];
  int tid = threadIdx.x, lane = tid & 63;
  int wv = tid >> 6, wm = wv >> 1, wn = wv & 1;
  __shared__ __attribute__((aligned(16))) short ldsA[128 * 32];
  __shared__ __attribute__((aligned(16))) short ldsB[128 * 40];
  __shared__ int stok[128];
  __shared__ float swt[128];
  if (tid < 128) {
    int srow = min(my * 128 + tid, cnt - 1);
    stok[tid] = slot_tok[slot0 + srow];
    swt[tid] = slot_w[slot0 + srow];
  }
  const short* ap[2]; short* la[2];
#pragma unroll
  for (int i = 0; i < 2; ++i) {
    int c = tid + i * 256;
    int row = c >> 2;
    int srow = min(my * 128 + row, cnt - 1);
    ap[i] = h + (size_t)(slot0 + srow) * HID + (c & 3) * 8;
    la[i] = &ldsA[c * 8];
  }
  int n0 = (tid & 63) * 2;
  int kg = tid >> 6;
  const float* bp = W2 + ((size_t)e * HID + kg * 8) * DIM + bx * 128 + n0;
  short* lb0 = &ldsB[(n0) * 40 + kg * 8];
  short* lb1 = &ldsB[(n0 + 1) * 40 + kg * 8];
  f32x4 acc[4][4];
#pragma unroll
  for (int i = 0; i < 4; ++i)
#pragma unroll
    for (int j = 0; j < 4; ++j) acc[i][j] = (f32x4){0.f, 0.f, 0.f, 0.f};
#pragma unroll 2
  for (int kt = 0; kt < HID / 32; ++kt) {
    float2 fv[8];
#pragma unroll
    for (int kk = 0; kk < 8; ++kk) fv[kk] = *(const float2*)&bp[(size_t)kk * DIM];
    __syncthreads();
    gll16(ap[0], la[0]); gll16(ap[1], la[1]);
    s16x8 v0, v1;
#pragma unroll
    for (int kk = 0; kk < 8; ++kk) { v0[kk] = (short)f2bf(fv[kk].x); v1[kk] = (short)f2bf(fv[kk].y); }
    *(s16x8*)lb0 = v0; *(s16x8*)lb1 = v1;
    asm volatile("s_waitcnt vmcnt(0)" ::: "memory");
    __syncthreads();
    s16x8 aF[4], bF[4];
#pragma unroll
    for (int i = 0; i < 4; ++i)
      aF[i] = *(const s16x8*)&ldsA[(wm * 64 + i * 16 + (lane & 15)) * 32 + (lane >> 4) * 8];
#pragma unroll
    for (int j = 0; j < 4; ++j)
      bF[j] = *(const s16x8*)&ldsB[(wn * 64 + j * 16 + (lane & 15)) * 40 + (lane >> 4) * 8];
#pragma unroll
    for (int i = 0; i < 4; ++i)
#pragma unroll
      for (int j = 0; j < 4; ++j)
        acc[i][j] = __builtin_amdgcn_mfma_f32_16x16x32_bf16(aF[i], bF[j], acc[i][j], 0, 0, 0);
    ap[0] += 32; ap[1] += 32; bp += (size_t)32 * DIM;
  }
#pragma unroll
  for (int i = 0; i < 4; ++i)
#pragma unroll
    for (int r = 0; r < 4; ++r) {
      int row_l = wm * 64 + i * 16 + (lane >> 4) * 4 + r;
      int grow = my * 128 + row_l;
      if (grow < cnt) {
        int tok = stok[row_l];
        float wrow = swt[row_l];
#pragma unroll
        for (int j = 0; j < 4; ++j) {
          int col = bx * 128 + wn * 64 + j * 16 + (lane & 15);
          float y = acc[i][j][r] + b2[e * DIM + col];
          unsafeAtomicAdd(&out[(size_t)tok * DIM + col], wrow * y);
        }
      }
    }
}

extern "C" void kernel_launch(void* const* d_in, const int* in_sizes, int n_in,
                              void* d_out, int out_size, void* d_ws, size_t ws_size,
                              hipStream_t stream) {
  const float* x  = (const float*)d_in[0];
  const float* Wr = (const float*)d_in[1];
  const float* br = (const float*)d_in[2];
  const float* W1 = (const float*)d_in[3];
  const float* b1 = (const float*)d_in[4];
  const float* W2 = (const float*)d_in[5];
  const float* b2 = (const float*)d_in[6];
  float* out = (float*)d_out;

  char* ws = (char*)d_ws;
  const size_t MiB = 1024 * 1024;
  int*   ctrl     = (int*)(ws);
  int*   sel      = (int*)(ws + 1024);
  float* selw     = (float*)(ws + 33792);
  int*   slot_tok = (int*)(ws + 66560);
  float* slot_w   = (float*)(ws + 99328);
  short* xbf      = (short*)(ws + 1 * MiB);    // 8 MiB
  short* h        = (short*)(ws + 16 * MiB);   // 64 MiB
  short* w1t      = (short*)(ws + 80 * MiB);   // 64 MiB  [e][HID][DIM] bf16
  short* w2t      = (short*)(ws + 144 * MiB);  // 64 MiB  [e][DIM][HID] bf16
  bool fat = ws_size >= 208 * MiB;

  zero_k<<<(NTOK * DIM / 4) / 256, 256, 0, stream>>>((float4*)out, ctrl);
  router_k<<<NTOK, 256, 0, stream>>>(x, Wr, br, xbf, ctrl, sel, selw);
  scan_k<<<1, 64, 0, stream>>>(ctrl);
  build_k<<<NTOK / 256, 256, 0, stream>>>(sel, selw, ctrl, slot_tok, slot_w);
  if (fat) {
    tcvt_k<<<dim3(HID / 64, DIM / 64, NE), 256, 0, stream>>>(W1, w1t, DIM, HID);
    tcvt_k<<<dim3(DIM / 64, HID / 64, NE), 256, 0, stream>>>(W2, w2t, HID, DIM);
    gemm1n_k<<<32 * 32 * NE, 256, 0, stream>>>(xbf, w1t, b1, ctrl, slot_tok, h);
    gemm2n_k<<<8 * 32 * NE * 2, 256, 0, stream>>>(h, w2t, b2, ctrl, slot_tok, slot_w, out);
  } else {
    gemm1_k<<<dim3(HID / 128, NTOK / 128, NE), 256, 0, stream>>>(xbf, W1, b1, ctrl, slot_tok, h);
    gemm2_k<<<dim3(DIM / 128, NTOK / 128, NE), 256, 0, stream>>>(h, W2, b2, ctrl, slot_tok, slot_w, out);
  }
}